// Round 9
// baseline (186.276 us; speedup 1.0000x reference)
//
#include <hip/hip_runtime.h>
#include <math.h>

#define LLEN   2048
#define NFFT   4096
#define DMODEL 256
#define NSTATE 64
#define NBATCH 16
#define PI_F   3.14159265358979323846f

#define PADIDX(a) ((a) + ((a) >> 4))
#define LDSN2 (LLEN + (LLEN >> 4))   // 2176 float2 (k_mixH, padded scheme)
#define KSTRIDE 2056                 // per-channel stride for Hc (f2)
#define TW16OFF (16 * 256)           // TW256 [t][256] then TW16 [t][16]

// XOR bank-swizzle for the 4096-pt FFT buffer (unpadded 32KB -> 5 blocks/CU).
#define SWZIDX(a) ((a) ^ (((a) >> 4) & 15))

__device__ inline float frcp(float x) { return __builtin_amdgcn_rcpf(x); }

#define RADIX4(ar0,ai0,ar1,ai1,ar2,ai2,ar3,ai3,S) do {                      \
    float s0r=(ar0)+(ar2), s0i=(ai0)+(ai2);                                 \
    float s1r=(ar0)-(ar2), s1i=(ai0)-(ai2);                                 \
    float s2r=(ar1)+(ar3), s2i=(ai1)+(ai3);                                 \
    float s3r=(ar1)-(ar3), s3i=(ai1)-(ai3);                                 \
    (ar0)=s0r+s2r; (ai0)=s0i+s2i;                                           \
    (ar2)=s0r-s2r; (ai2)=s0i-s2i;                                           \
    (ar1)=s1r-(S)*s3i; (ai1)=s1i+(S)*s3r;                                   \
    (ar3)=s1r+(S)*s3i; (ai3)=s1i-(S)*s3r;                                   \
} while (0)

// common tail of the 16-pt DFT: twiddles + second radix-4 layer.
// Output X[u] (u = k0 + 4*k2) lands in slot 4*k0 + k2.
template<int SIGN>
__device__ inline void dft16_tail(float xr[16], float xi[16]) {
    const float S = (float)SIGN;
    const float C1 = 0.9238795325112867f, S1 = 0.3826834323650898f;
    const float C2 = 0.7071067811865476f;
#define TW(idx, wr_, wi_) { float tr = xr[idx]*(wr_) - xi[idx]*(wi_);       \
    xi[idx] = xr[idx]*(wi_) + xi[idx]*(wr_); xr[idx] = tr; }
    TW(5,  C1,  S*S1);
    TW(6,  C2,  S*C2);
    TW(7,  S1,  S*C1);
    TW(9,  C2,  S*C2);
    TW(10, 0.f, S);
    TW(11, -C2, S*C2);
    TW(13, S1,  S*C1);
    TW(14, -C2, S*C2);
    TW(15, -C1, -S*S1);
#undef TW
    RADIX4(xr[0],xi[0],  xr[1],xi[1],  xr[2],xi[2],  xr[3],xi[3],  S);
    RADIX4(xr[4],xi[4],  xr[5],xi[5],  xr[6],xi[6],  xr[7],xi[7],  S);
    RADIX4(xr[8],xi[8],  xr[9],xi[9],  xr[10],xi[10],xr[11],xi[11],S);
    RADIX4(xr[12],xi[12],xr[13],xi[13],xr[14],xi[14],xr[15],xi[15],S);
}

template<int SIGN>
__device__ inline void dft16(float xr[16], float xi[16]) {
    const float S = (float)SIGN;
    RADIX4(xr[0],xi[0], xr[4],xi[4], xr[8],xi[8],  xr[12],xi[12], S);
    RADIX4(xr[1],xi[1], xr[5],xi[5], xr[9],xi[9],  xr[13],xi[13], S);
    RADIX4(xr[2],xi[2], xr[6],xi[6], xr[10],xi[10],xr[14],xi[14], S);
    RADIX4(xr[3],xi[3], xr[7],xi[7], xr[11],xi[11],xr[15],xi[15], S);
    dft16_tail<SIGN>(xr, xi);
}

// 16-point DFT with inputs 8..15 KNOWN ZERO (not read).
template<int SIGN>
__device__ inline void dft16z(float xr[16], float xi[16]) {
    const float S = (float)SIGN;
#define RAD4Z(r0,i0,r1,i1,r2,i2,r3,i3) do {                                 \
    const float a0r=(r0), a0i=(i0), a1r=(r1), a1i=(i1);                     \
    (r0)=a0r+a1r;     (i0)=a0i+a1i;                                         \
    (r2)=a0r-a1r;     (i2)=a0i-a1i;                                         \
    (r1)=a0r-S*a1i;   (i1)=a0i+S*a1r;                                       \
    (r3)=a0r+S*a1i;   (i3)=a0i-S*a1r;                                       \
} while (0)
    RAD4Z(xr[0],xi[0], xr[4],xi[4], xr[8],xi[8],  xr[12],xi[12]);
    RAD4Z(xr[1],xi[1], xr[5],xi[5], xr[9],xi[9],  xr[13],xi[13]);
    RAD4Z(xr[2],xi[2], xr[6],xi[6], xr[10],xi[10],xr[14],xi[14]);
    RAD4Z(xr[3],xi[3], xr[7],xi[7], xr[11],xi[11],xr[15],xi[15]);
#undef RAD4Z
    dft16_tail<SIGN>(xr, xi);
}

template<int SIGN>
__device__ inline void dft8(float xr[8], float xi[8]) {
    const float S = (float)SIGN;
    const float C2 = 0.7071067811865476f;
    RADIX4(xr[0],xi[0], xr[2],xi[2], xr[4],xi[4], xr[6],xi[6], S);
    RADIX4(xr[1],xi[1], xr[3],xi[3], xr[5],xi[5], xr[7],xi[7], S);
    { float tr = xr[3]*C2 - xi[3]*(S*C2); xi[3] = xr[3]*(S*C2) + xi[3]*C2; xr[3] = tr; }
    { float tr = -S*xi[5]; xi[5] = S*xr[5]; xr[5] = tr; }
    { float tr = xr[7]*(-C2) - xi[7]*(S*C2); xi[7] = xr[7]*(S*C2) + xi[7]*(-C2); xr[7] = tr; }
    float br[8], bi[8];
#pragma unroll
    for (int k = 0; k < 4; ++k) {
        br[k]   = xr[2*k] + xr[2*k+1]; bi[k]   = xi[2*k] + xi[2*k+1];
        br[k+4] = xr[2*k] - xr[2*k+1]; bi[k+4] = xi[2*k] - xi[2*k+1];
    }
#pragma unroll
    for (int k = 0; k < 8; ++k) { xr[k] = br[k]; xi[k] = bi[k]; }
}

// power chain w^2..w^15 from w^1 (the exact chain the kernels used in-line).
__device__ inline void tw_chain(float wr[16], float wi[16]) {
#pragma unroll
    for (int k = 1; k < 8; ++k) {
        wr[2*k]   = wr[k]*wr[k] - wi[k]*wi[k];
        wi[2*k]   = 2.f * wr[k] * wi[k];
        wr[2*k+1] = wr[k]*wr[k+1] - wi[k]*wi[k+1];
        wi[2*k+1] = wr[k]*wi[k+1] + wi[k]*wr[k+1];
    }
}

template<int SIGN>
__device__ inline void tw_apply16(float xr[16], float xi[16], float ang) {
    float wr[16], wi[16];
    __sincosf(ang, &wi[1], &wr[1]);
    tw_chain(wr, wi);
#pragma unroll
    for (int t = 1; t < 16; ++t) {
        float tr = xr[t]*wr[t] - xi[t]*wi[t];
        xi[t] = xr[t]*wi[t] + xi[t]*wr[t];
        xr[t] = tr;
    }
}

// ---------------- padded-index stages (2048-pt path, k_mixH only) ------------
template<int SIGN, int M, int L, bool PRUNE>
__device__ inline void stage16(float2* X, int j, bool active) {
    float xr[16], xi[16];
    const int p = j & (L - 1);
    if (active) {
#pragma unroll
        for (int t = 0; t < 16; ++t) {
            float2 v = X[PADIDX(j + t * M)];
            xr[t] = v.x; xi[t] = v.y;
        }
        tw_apply16<SIGN>(xr, xi, ((float)SIGN * 2.f * PI_F / (float)(16 * L)) * (float)p);
        dft16<SIGN>(xr, xi);
    }
    __syncthreads();
    if (active) {
        const int base = 16 * j - 15 * p;
#pragma unroll
        for (int k0 = 0; k0 < 4; ++k0)
#pragma unroll
            for (int k2 = 0; k2 < 4; ++k2) {
                const int u = k0 + 4 * k2;
                if (!PRUNE || u < 8) {
                    const int a = base + u * L;
                    X[PADIDX(a)] = make_float2(xr[4*k0+k2], xi[4*k0+k2]);
                }
            }
    }
    __syncthreads();
}

// 2048-pt FFT, radices [8,16,16] (padded indexing; used by k_mixH)
template<int SIGN>
__device__ inline void fft2048_f2(float2* X, int tid) {
    float xr[8], xi[8];
#pragma unroll
    for (int t = 0; t < 8; ++t) {
        float2 v = X[PADIDX(tid + t * 256)];
        xr[t] = v.x; xi[t] = v.y;
    }
    dft8<SIGN>(xr, xi);
    __syncthreads();
#pragma unroll
    for (int u = 0; u < 8; ++u)
        X[PADIDX(8 * tid + u)] = make_float2(xr[u], xi[u]);
    __syncthreads();
    stage16<SIGN, 128, 8,   false>(X, tid, tid < 128);
    stage16<SIGN, 128, 128, false>(X, tid, tid < 128);
}

// ------------- XOR-swizzled, TABLE-twiddled stages (4096-pt, k_conv) ---------
// twrow: t-major table [t][L] storing SIGN=-1 twiddles; inverse applies conj
// via compile-time sign flip. Coalesced: consecutive p across lanes.
template<int SIGN, int M, int L, bool PRUNE>
__device__ inline void stage16t(float2* X, int j, const float2* __restrict__ twrow) {
    float xr[16], xi[16];
    const int p = j & (L - 1);
    float2 w[16];
#pragma unroll
    for (int t = 1; t < 16; ++t)
        w[t] = twrow[t * L + p];
#pragma unroll
    for (int t = 0; t < 16; ++t) {
        float2 v = X[SWZIDX(j + t * M)];
        xr[t] = v.x; xi[t] = v.y;
    }
#pragma unroll
    for (int t = 1; t < 16; ++t) {
        const float wx = w[t].x;
        const float wy = (SIGN == -1) ? w[t].y : -w[t].y;
        const float tr = xr[t]*wx - xi[t]*wy;
        xi[t] = xr[t]*wy + xi[t]*wx;
        xr[t] = tr;
    }
    dft16<SIGN>(xr, xi);
    __syncthreads();
    const int base = 16 * j - 15 * p;
#pragma unroll
    for (int k0 = 0; k0 < 4; ++k0)
#pragma unroll
        for (int k2 = 0; k2 < 4; ++k2) {
            const int u = k0 + 4 * k2;
            if (!PRUNE || u < 8) {
                const int a = base + u * L;
                X[SWZIDX(a)] = make_float2(xr[4*k0+k2], xi[4*k0+k2]);
            }
        }
    __syncthreads();
}

// forward 4096-pt FFT, stage-0 input in registers (upper half structurally 0).
template<int SIGN, bool PRUNE>
__device__ inline void fft4096_swz_from_regs(float2* X, int tid,
                                             float xr[16], float xi[16],
                                             const float2* __restrict__ tw) {
    dft16z<SIGN>(xr, xi);
#pragma unroll
    for (int k0 = 0; k0 < 4; ++k0)
#pragma unroll
        for (int k2 = 0; k2 < 4; ++k2)
            X[SWZIDX(16 * tid + k0 + 4 * k2)] = make_float2(xr[4*k0+k2], xi[4*k0+k2]);
    __syncthreads();
    stage16t<SIGN, 256, 16,  false>(X, tid, tw + TW16OFF);
    stage16t<SIGN, 256, 256, PRUNE>(X, tid, tw);
}

// full 4096-pt FFT from LDS (inverse path). PRUNE: only outputs idx<2048 stored.
template<int SIGN, bool PRUNE>
__device__ inline void fft4096_swz(float2* X, int tid,
                                   const float2* __restrict__ tw) {
    float xr[16], xi[16];
#pragma unroll
    for (int t = 0; t < 16; ++t) {
        float2 v = X[SWZIDX(tid + t * 256)];
        xr[t] = v.x; xi[t] = v.y;
    }
    dft16<SIGN>(xr, xi);
    __syncthreads();
#pragma unroll
    for (int k0 = 0; k0 < 4; ++k0)
#pragma unroll
        for (int k2 = 0; k2 < 4; ++k2)
            X[SWZIDX(16 * tid + k0 + 4 * k2)] = make_float2(xr[4*k0+k2], xi[4*k0+k2]);
    __syncthreads();
    stage16t<SIGN, 256, 16,  false>(X, tid, tw + TW16OFF);
    stage16t<SIGN, 256, 256, PRUNE>(X, tid, tw);
}

// ---- K_pre: blocks [0,512)   = at_roots (k_ar, dispatched FIRST for spread);
//             blocks [512,2560)= 64x64 float4 transpose of u (BW-bound backfill);
//             block  2560      = twiddle table build.
//      Block-level co-scheduling: latency-bound k_ar waves hide under the
//      transpose's BW waits (unlike r7's failed intra-block fusion).
__global__ __launch_bounds__(256) void k_pre(const float* __restrict__ u,
                                             const float* __restrict__ p_ri,
                                             const float* __restrict__ lambda_ri,
                                             const float* __restrict__ B_ri,
                                             const float* __restrict__ Ct_ri,
                                             const float* __restrict__ log_step,
                                             float2* __restrict__ a_out,
                                             float* __restrict__ ut,
                                             float2* __restrict__ tw) {
    __shared__ float4 shbuf[1040];      // 16640 B, aliased per-branch
    const int bid = blockIdx.x;
    const int tid = threadIdx.x;

    if (bid < DMODEL * 2) {
        // ---- at_roots: 4 l's per thread --------------------------------------
        float4* c0 = shbuf;             // [64]
        float4* c1 = shbuf + 64;        // [64]
        float2* lam = (float2*)(shbuf + 128);
        const int d = bid >> 1;
        const int lbase = (bid & 1) << 10;
        if (tid < NSTATE) {
            const int n = tid;
            const float px = p_ri[2*n], py = p_ri[2*n+1];
            lam[n] = make_float2(lambda_ri[2*n], lambda_ri[2*n+1]);
            const float Bx = B_ri[(d*NSTATE+n)*2], By = B_ri[(d*NSTATE+n)*2+1];
            const float Cx = Ct_ri[(d*NSTATE+n)*2], Cy = Ct_ri[(d*NSTATE+n)*2+1];
            c0[n] = make_float4(Cx*Bx + Cy*By, Cx*By - Cy*Bx,
                                Cx*px + Cy*py, Cx*py - Cy*px);
            c1[n] = make_float4(px*Bx + py*By, px*By - py*Bx, px*px + py*py, 0.f);
        }
        __syncthreads();

        const float tos = 2.f * __expf(-log_step[d]);
        float gx[4], gy[4], ccx[4], ccy[4];
        float k00x[4], k00y[4], k01x[4], k01y[4];
        float k10x[4], k10y[4], k11x[4], k11y[4];
#pragma unroll
        for (int j = 0; j < 4; ++j) {
            const int l = lbase + tid + (j << 8);
            float sn, cs;
            sincosf(2.f * PI_F * (float)l / (float)LLEN, &sn, &cs);
            const float opx = 1.f + cs, opy = sn;
            const float omx = 1.f - cs, omy = -sn;
            const float inv_op = frcp(opx*opx + opy*opy);
            gx[j] = tos * (omx*opx + omy*opy) * inv_op;
            gy[j] = tos * (omy*opx - omx*opy) * inv_op;
            ccx[j] = 2.f * opx * inv_op; ccy[j] = -2.f * opy * inv_op;
            k00x[j]=0.f; k00y[j]=0.f; k01x[j]=0.f; k01y[j]=0.f;
            k10x[j]=0.f; k10y[j]=0.f; k11x[j]=0.f; k11y[j]=0.f;
        }
        for (int n = 0; n < NSTATE; ++n) {
            const float2 lm = lam[n];
            const float4 a = c0[n];
            const float4 b = c1[n];
#pragma unroll
            for (int j = 0; j < 4; ++j) {
                const float dx = gx[j] - lm.x, dy = gy[j] - lm.y;
                const float idn = frcp(dx*dx + dy*dy);
                const float ix = dx * idn, iy = -dy * idn;
                k00x[j] += a.x*ix - a.y*iy;  k00y[j] += a.x*iy + a.y*ix;
                k01x[j] += a.z*ix - a.w*iy;  k01y[j] += a.z*iy + a.w*ix;
                k10x[j] += b.x*ix - b.y*iy;  k10y[j] += b.x*iy + b.y*ix;
                k11x[j] += b.z*ix;           k11y[j] += b.z*iy;
            }
        }
#pragma unroll
        for (int j = 0; j < 4; ++j) {
            const float nx = k01x[j]*k10x[j] - k01y[j]*k10y[j];
            const float ny = k01x[j]*k10y[j] + k01y[j]*k10x[j];
            const float dpx = 1.f + k11x[j], dpy = k11y[j];
            const float idq = frcp(dpx*dpx + dpy*dpy);
            const float qx = (nx*dpx + ny*dpy) * idq;
            const float qy = (ny*dpx - nx*dpy) * idq;
            const float rx = k00x[j] - qx, ry = k00y[j] - qy;
            a_out[(size_t)d * LLEN + lbase + tid + (j << 8)] =
                make_float2(ccx[j]*rx - ccy[j]*ry, ccx[j]*ry + ccy[j]*rx);
        }
        return;
    }

    if (bid < DMODEL * 2 + 2048) {
        // ---- 64x64 float4-both-sides transpose ------------------------------
        const int blk = bid - DMODEL * 2;           // 0..2047
        const int bt0 = (blk & 511) * 64;
        const int ch0 = (blk >> 9) * 64;
        float* tile = (float*)shbuf;                // 64 x 65 floats
        const int tx4 = (tid & 15) * 4;
        const int ty  = tid >> 4;
#pragma unroll
        for (int k = 0; k < 4; ++k) {
            const int r = ty + 16 * k;
            const float4 v = *(const float4*)&u[(size_t)(bt0 + r) * DMODEL + ch0 + tx4];
            tile[r * 65 + tx4 + 0] = v.x;
            tile[r * 65 + tx4 + 1] = v.y;
            tile[r * 65 + tx4 + 2] = v.z;
            tile[r * 65 + tx4 + 3] = v.w;
        }
        __syncthreads();
#pragma unroll
        for (int k = 0; k < 4; ++k) {
            const int c = ty + 16 * k;
            float4 o;
            o.x = tile[(tx4 + 0) * 65 + c];
            o.y = tile[(tx4 + 1) * 65 + c];
            o.z = tile[(tx4 + 2) * 65 + c];
            o.w = tile[(tx4 + 3) * 65 + c];
            *(float4*)&ut[(size_t)(ch0 + c) * (NBATCH * LLEN) + bt0 + tx4] = o;
        }
        return;
    }

    // ---- twiddle table build (1 block). Same chain as tw_apply16 -> numerics
    //      identical to the previous in-line computation. SIGN=-1 stored. ----
    {
        float wr[16], wi[16];
        __sincosf(-2.f * PI_F * (float)tid * (1.f / 4096.f), &wi[1], &wr[1]);
        tw_chain(wr, wi);
#pragma unroll
        for (int t = 1; t < 16; ++t)
            tw[t * 256 + tid] = make_float2(wr[t], wi[t]);
        if (tid < 16) {
            __sincosf(-2.f * PI_F * (float)tid * (1.f / 256.f), &wi[1], &wr[1]);
            tw_chain(wr, wi);
#pragma unroll
            for (int t = 1; t < 16; ++t)
                tw[TW16OFF + t * 16 + tid] = make_float2(wr[t], wi[t]);
        }
    }
}

// ---- K_mixH: Khat from a (2x FFT2048 via even/odd identity), 256 blocks -----
__global__ __launch_bounds__(256, 4) void k_mixH(const float2* __restrict__ a_in,
                                                 float2* __restrict__ Hc) {
    __shared__ float2 X[LDSN2];
    const int tid = threadIdx.x;
    const int d = blockIdx.x;
    const float isc = 1.f / (float)NFFT;
    const float4* a4 = (const float4*)(a_in + (size_t)d * LLEN);
#pragma unroll
    for (int k = 0; k < 4; ++k) {
        const int v = tid + k * 256;
        const float4 w = a4[v];
        X[PADIDX(2 * v)]     = make_float2(w.x, w.y);
        X[PADIDX(2 * v + 1)] = make_float2(w.z, w.w);
    }
    __syncthreads();

    float2* H = Hc + (size_t)d * KSTRIDE;
    // even frequencies: Khat_{2m} = (a_{(-m) mod L} + conj(a_m)) / 2
    for (int m = tid; m <= 1024; m += 256) {
        const float2 am = X[PADIDX(m)];
        const float2 an = X[PADIDX((LLEN - m) & (LLEN - 1))];
        H[2 * m] = make_float2((an.x + am.x) * 0.5f * isc,
                               (an.y - am.y) * 0.5f * isc);
    }
    fft2048_f2<-1>(X, tid);     // A = F(a)

    // K_j = Re(A_j)/L ; modulate by e^{-2*pi*i*j/4096}
#pragma unroll
    for (int k = 0; k < 8; ++k) {
        const int j = tid + k * 256;
        const int q = PADIDX(j);
        const float Kj = X[q].x * (1.f / (float)LLEN);
        float snj, csj;
        __sincosf(-PI_F * (float)j * (1.f / 2048.f), &snj, &csj);
        X[q] = make_float2(Kj * csj, Kj * snj);
    }
    __syncthreads();
    fft2048_f2<-1>(X, tid);     // W_m = Khat_{2m+1}

    for (int m = tid; m < 1024; m += 256) {
        const float2 w = X[PADIDX(m)];
        H[2 * m + 1] = make_float2(w.x * isc, w.y * isc);
    }
}

// ---- K_conv: per (channel, batch-pair). Swizzled 32KB LDS, register-entry
//      stage-0 (dft16z), TABLE twiddles, fused skip-add, float4 epilogue.
//      XCD swizzle: XCD x owns channels [32x,32x+32) with all 8 pairs.
__global__ __launch_bounds__(256, 4) void k_conv(const float* __restrict__ ut,
                                                 const float2* __restrict__ Hc,
                                                 const float* __restrict__ Dp,
                                                 const float2* __restrict__ tw,
                                                 float* __restrict__ yt) {
    __shared__ float2 X[NFFT];            // 32768 B, unpadded (SWZIDX everywhere)
    const int bid = blockIdx.x;           // 0..2047
    const int x = bid & 7;                // xcd (dispatch round-robins)
    const int s = bid >> 3;               // 0..255
    const int ch = (x << 5) | (s & 31);   // channel 0..255
    const int pair = s >> 5;              // 0..7
    const int tid = threadIdx.x;

    const float* u0 = ut + (size_t)ch * (NBATCH * LLEN) + (size_t)(2 * pair) * LLEN;
    const float* u1 = u0 + LLEN;

    float xr[16], xi[16];
#pragma unroll
    for (int k = 0; k < 8; ++k) {         // coalesced: 64 lanes x 4B dense
        xr[k] = u0[tid + k * 256];
        xi[k] = u1[tid + k * 256];
    }
    // xr/xi[8..15] are structurally zero and never read (dft16z)

    fft4096_swz_from_regs<-1, false>(X, tid, xr, xi, tw);

    const float2* H = Hc + (size_t)ch * KSTRIDE;
    for (int f = tid; f <= NFFT / 2; f += 256) {
        const int fb = (NFFT - f) & (NFFT - 1);
        const float2 Za = X[SWZIDX(f)], Zb = X[SWZIDX(fb)];
        const float u0x = 0.5f * (Za.x + Zb.x), u0y = 0.5f * (Za.y - Zb.y);
        const float u1x = 0.5f * (Za.y + Zb.y), u1y = -0.5f * (Za.x - Zb.x);
        const float2 Ha = H[f];
        const float y0x = u0x*Ha.x - u0y*Ha.y, y0y = u0x*Ha.y + u0y*Ha.x;
        const float y1x = u1x*Ha.x - u1y*Ha.y, y1y = u1x*Ha.y + u1y*Ha.x;
        X[SWZIDX(f)] = make_float2(y0x - y1y, y0y + y1x);
        if (fb != f) {
            const float Hbx = Ha.x, Hby = -Ha.y;   // H[fb] = conj(H[f]) (K real)
            const float z0x = u0x*Hbx + u0y*Hby, z0y = u0x*Hby - u0y*Hbx;
            const float z1x = u1x*Hbx + u1y*Hby, z1y = u1x*Hby - u1y*Hbx;
            X[SWZIDX(fb)] = make_float2(z0x - z1y, z0y + z1x);
        }
    }
    __syncthreads();
    fft4096_swz<+1, true>(X, tid, tw);    // pruned: only t<2048 stored

    const float dp = Dp[ch];
    float* y0o = yt + (size_t)ch * (NBATCH * LLEN) + (size_t)(2 * pair) * LLEN;
    float* y1o = y0o + LLEN;
#pragma unroll
    for (int k = 0; k < 2; ++k) {
        const int i0 = 4 * (tid + k * 256);           // 4-aligned, <2048
        const float2 va = X[SWZIDX(i0 + 0)];
        const float2 vb = X[SWZIDX(i0 + 1)];
        const float2 vc = X[SWZIDX(i0 + 2)];
        const float2 vd = X[SWZIDX(i0 + 3)];
        const float4 u0v = *(const float4*)&u0[i0];
        const float4 u1v = *(const float4*)&u1[i0];
        float4 o0, o1;
        o0.x = va.x + dp * u0v.x; o0.y = vb.x + dp * u0v.y;
        o0.z = vc.x + dp * u0v.z; o0.w = vd.x + dp * u0v.w;
        o1.x = va.y + dp * u1v.x; o1.y = vb.y + dp * u1v.y;
        o1.z = vc.y + dp * u1v.z; o1.w = vd.y + dp * u1v.w;
        *(float4*)&y0o[i0] = o0;
        *(float4*)&y1o[i0] = o1;
    }
}

// ---- K_post: 64x64 float4-both-sides transpose yt -> out ---------------------
__global__ __launch_bounds__(256) void k_post(const float* __restrict__ yt,
                                              float* __restrict__ out) {
    __shared__ float tile[64 * 65];       // 16640 B
    const int bt0 = (blockIdx.x & 511) * 64;
    const int ch0 = (blockIdx.x >> 9) * 64;
    const int tid = threadIdx.x;
    const int tx4 = (tid & 15) * 4;
    const int ty  = tid >> 4;
#pragma unroll
    for (int k = 0; k < 4; ++k) {
        const int r = ty + 16 * k;        // ch row 0..63
        const float4 v = *(const float4*)&yt[(size_t)(ch0 + r) * (NBATCH * LLEN) + bt0 + tx4];
        tile[r * 65 + tx4 + 0] = v.x;
        tile[r * 65 + tx4 + 1] = v.y;
        tile[r * 65 + tx4 + 2] = v.z;
        tile[r * 65 + tx4 + 3] = v.w;
    }
    __syncthreads();
#pragma unroll
    for (int k = 0; k < 4; ++k) {
        const int b = ty + 16 * k;        // bt row 0..63
        float4 o;
        o.x = tile[(tx4 + 0) * 65 + b];
        o.y = tile[(tx4 + 1) * 65 + b];
        o.z = tile[(tx4 + 2) * 65 + b];
        o.w = tile[(tx4 + 3) * 65 + b];
        *(float4*)&out[(size_t)(bt0 + b) * DMODEL + ch0 + tx4] = o;
    }
}

extern "C" void kernel_launch(void* const* d_in, const int* in_sizes, int n_in,
                              void* d_out, int out_size, void* d_ws, size_t ws_size,
                              hipStream_t stream) {
    const float* u         = (const float*)d_in[0];
    const float* p_ri      = (const float*)d_in[1];
    const float* lambda_ri = (const float*)d_in[2];
    const float* B_ri      = (const float*)d_in[3];
    const float* Ct_ri     = (const float*)d_in[4];
    const float* Dp        = (const float*)d_in[5];
    const float* log_step  = (const float*)d_in[6];
    float* out = (float*)d_out;

    // ws layout: Hc (4.21MB) | region B: a (4MB) aliased by yt (33.5MB) | tw (34KB)
    float2* Hc = (float2*)d_ws;
    char*   wb = (char*)d_ws + (size_t)DMODEL * KSTRIDE * sizeof(float2);
    float2* a  = (float2*)wb;
    float*  yt = (float*)wb;
    float2* tw = (float2*)(wb + (size_t)DMODEL * NBATCH * LLEN * sizeof(float));
    float*  ut = out;   // d_out doubles as transpose scratch (overwritten by k_post)

    k_pre <<<DMODEL * 2 + 2048 + 1, 256, 0, stream>>>(u, p_ri, lambda_ri, B_ri,
                                                      Ct_ri, log_step, a, ut, tw);
    k_mixH<<<DMODEL, 256, 0, stream>>>(a, Hc);
    k_conv<<<DMODEL * (NBATCH / 2), 256, 0, stream>>>(ut, Hc, Dp, tw, yt);
    k_post<<<2048, 256, 0, stream>>>(yt, out);
}

// Round 10
// 170.018 us; speedup vs baseline: 1.0956x; 1.0956x over previous
//
#include <hip/hip_runtime.h>
#include <math.h>

#define LLEN   2048
#define NFFT   4096
#define DMODEL 256
#define NSTATE 64
#define NBATCH 16
#define PI_F   3.14159265358979323846f

#define PADIDX(a) ((a) + ((a) >> 4))
#define LDSN2 (LLEN + (LLEN >> 4))   // 2176 float2 (k_mixH, padded scheme)
#define KSTRIDE 2056                 // per-channel stride for Hc (f2)

// XOR bank-swizzle for the 4096-pt FFT buffer (unpadded 32KB -> 5 blocks/CU).
// Involution; applied identically on every read & write. Verified r3/r5/r6/r8.
#define SWZIDX(a) ((a) ^ (((a) >> 4) & 15))

__device__ inline float frcp(float x) { return __builtin_amdgcn_rcpf(x); }

#define RADIX4(ar0,ai0,ar1,ai1,ar2,ai2,ar3,ai3,S) do {                      \
    float s0r=(ar0)+(ar2), s0i=(ai0)+(ai2);                                 \
    float s1r=(ar0)-(ar2), s1i=(ai0)-(ai2);                                 \
    float s2r=(ar1)+(ar3), s2i=(ai1)+(ai3);                                 \
    float s3r=(ar1)-(ar3), s3i=(ai1)-(ai3);                                 \
    (ar0)=s0r+s2r; (ai0)=s0i+s2i;                                           \
    (ar2)=s0r-s2r; (ai2)=s0i-s2i;                                           \
    (ar1)=s1r-(S)*s3i; (ai1)=s1i+(S)*s3r;                                   \
    (ar3)=s1r+(S)*s3i; (ai3)=s1i-(S)*s3r;                                   \
} while (0)

// common tail of the 16-pt DFT: twiddles + second radix-4 layer.
// Output X[u] (u = k0 + 4*k2) lands in slot 4*k0 + k2.
template<int SIGN>
__device__ inline void dft16_tail(float xr[16], float xi[16]) {
    const float S = (float)SIGN;
    const float C1 = 0.9238795325112867f, S1 = 0.3826834323650898f;
    const float C2 = 0.7071067811865476f;
#define TW(idx, wr_, wi_) { float tr = xr[idx]*(wr_) - xi[idx]*(wi_);       \
    xi[idx] = xr[idx]*(wi_) + xi[idx]*(wr_); xr[idx] = tr; }
    TW(5,  C1,  S*S1);
    TW(6,  C2,  S*C2);
    TW(7,  S1,  S*C1);
    TW(9,  C2,  S*C2);
    TW(10, 0.f, S);
    TW(11, -C2, S*C2);
    TW(13, S1,  S*C1);
    TW(14, -C2, S*C2);
    TW(15, -C1, -S*S1);
#undef TW
    RADIX4(xr[0],xi[0],  xr[1],xi[1],  xr[2],xi[2],  xr[3],xi[3],  S);
    RADIX4(xr[4],xi[4],  xr[5],xi[5],  xr[6],xi[6],  xr[7],xi[7],  S);
    RADIX4(xr[8],xi[8],  xr[9],xi[9],  xr[10],xi[10],xr[11],xi[11],S);
    RADIX4(xr[12],xi[12],xr[13],xi[13],xr[14],xi[14],xr[15],xi[15],S);
}

template<int SIGN>
__device__ inline void dft16(float xr[16], float xi[16]) {
    const float S = (float)SIGN;
    RADIX4(xr[0],xi[0], xr[4],xi[4], xr[8],xi[8],  xr[12],xi[12], S);
    RADIX4(xr[1],xi[1], xr[5],xi[5], xr[9],xi[9],  xr[13],xi[13], S);
    RADIX4(xr[2],xi[2], xr[6],xi[6], xr[10],xi[10],xr[14],xi[14], S);
    RADIX4(xr[3],xi[3], xr[7],xi[7], xr[11],xi[11],xr[15],xi[15], S);
    dft16_tail<SIGN>(xr, xi);
}

// 16-point DFT with inputs 8..15 KNOWN ZERO (not read).
template<int SIGN>
__device__ inline void dft16z(float xr[16], float xi[16]) {
    const float S = (float)SIGN;
#define RAD4Z(r0,i0,r1,i1,r2,i2,r3,i3) do {                                 \
    const float a0r=(r0), a0i=(i0), a1r=(r1), a1i=(i1);                     \
    (r0)=a0r+a1r;     (i0)=a0i+a1i;                                         \
    (r2)=a0r-a1r;     (i2)=a0i-a1i;                                         \
    (r1)=a0r-S*a1i;   (i1)=a0i+S*a1r;                                       \
    (r3)=a0r+S*a1i;   (i3)=a0i-S*a1r;                                       \
} while (0)
    RAD4Z(xr[0],xi[0], xr[4],xi[4], xr[8],xi[8],  xr[12],xi[12]);
    RAD4Z(xr[1],xi[1], xr[5],xi[5], xr[9],xi[9],  xr[13],xi[13]);
    RAD4Z(xr[2],xi[2], xr[6],xi[6], xr[10],xi[10],xr[14],xi[14]);
    RAD4Z(xr[3],xi[3], xr[7],xi[7], xr[11],xi[11],xr[15],xi[15]);
#undef RAD4Z
    dft16_tail<SIGN>(xr, xi);
}

template<int SIGN>
__device__ inline void dft8(float xr[8], float xi[8]) {
    const float S = (float)SIGN;
    const float C2 = 0.7071067811865476f;
    RADIX4(xr[0],xi[0], xr[2],xi[2], xr[4],xi[4], xr[6],xi[6], S);
    RADIX4(xr[1],xi[1], xr[3],xi[3], xr[5],xi[5], xr[7],xi[7], S);
    { float tr = xr[3]*C2 - xi[3]*(S*C2); xi[3] = xr[3]*(S*C2) + xi[3]*C2; xr[3] = tr; }
    { float tr = -S*xi[5]; xi[5] = S*xr[5]; xr[5] = tr; }
    { float tr = xr[7]*(-C2) - xi[7]*(S*C2); xi[7] = xr[7]*(S*C2) + xi[7]*(-C2); xr[7] = tr; }
    float br[8], bi[8];
#pragma unroll
    for (int k = 0; k < 4; ++k) {
        br[k]   = xr[2*k] + xr[2*k+1]; bi[k]   = xi[2*k] + xi[2*k+1];
        br[k+4] = xr[2*k] - xr[2*k+1]; bi[k+4] = xi[2*k] - xi[2*k+1];
    }
#pragma unroll
    for (int k = 0; k < 8; ++k) { xr[k] = br[k]; xi[k] = bi[k]; }
}

// In-line twiddle generation: lives in the same registers the butterflies
// recycle. r9 proved a memory table SPILLS (core sits at the 64-VGPR point).
template<int SIGN>
__device__ inline void tw_apply16(float xr[16], float xi[16], float ang) {
    float wr[16], wi[16];
    __sincosf(ang, &wi[1], &wr[1]);
#pragma unroll
    for (int k = 1; k < 8; ++k) {
        wr[2*k]   = wr[k]*wr[k] - wi[k]*wi[k];
        wi[2*k]   = 2.f * wr[k] * wi[k];
        wr[2*k+1] = wr[k]*wr[k+1] - wi[k]*wi[k+1];
        wi[2*k+1] = wr[k]*wi[k+1] + wi[k]*wr[k+1];
    }
#pragma unroll
    for (int t = 1; t < 16; ++t) {
        float tr = xr[t]*wr[t] - xi[t]*wi[t];
        xi[t] = xr[t]*wi[t] + xi[t]*wr[t];
        xr[t] = tr;
    }
}

// ---------------- padded-index stages (2048-pt path, k_mixH only) ------------
template<int SIGN, int M, int L, bool PRUNE>
__device__ inline void stage16(float2* X, int j, bool active) {
    float xr[16], xi[16];
    const int p = j & (L - 1);
    if (active) {
#pragma unroll
        for (int t = 0; t < 16; ++t) {
            float2 v = X[PADIDX(j + t * M)];
            xr[t] = v.x; xi[t] = v.y;
        }
        tw_apply16<SIGN>(xr, xi, ((float)SIGN * 2.f * PI_F / (float)(16 * L)) * (float)p);
        dft16<SIGN>(xr, xi);
    }
    __syncthreads();
    if (active) {
        const int base = 16 * j - 15 * p;
#pragma unroll
        for (int k0 = 0; k0 < 4; ++k0)
#pragma unroll
            for (int k2 = 0; k2 < 4; ++k2) {
                const int u = k0 + 4 * k2;
                if (!PRUNE || u < 8) {
                    const int a = base + u * L;
                    X[PADIDX(a)] = make_float2(xr[4*k0+k2], xi[4*k0+k2]);
                }
            }
    }
    __syncthreads();
}

// 2048-pt FFT, radices [8,16,16] (padded indexing; used by k_mixH)
template<int SIGN>
__device__ inline void fft2048_f2(float2* X, int tid) {
    float xr[8], xi[8];
#pragma unroll
    for (int t = 0; t < 8; ++t) {
        float2 v = X[PADIDX(tid + t * 256)];
        xr[t] = v.x; xi[t] = v.y;
    }
    dft8<SIGN>(xr, xi);
    __syncthreads();
#pragma unroll
    for (int u = 0; u < 8; ++u)
        X[PADIDX(8 * tid + u)] = make_float2(xr[u], xi[u]);
    __syncthreads();
    stage16<SIGN, 128, 8,   false>(X, tid, tid < 128);
    stage16<SIGN, 128, 128, false>(X, tid, tid < 128);
}

// ---------------- XOR-swizzled stages (4096-pt path, k_conv) -----------------
template<int SIGN, int M, int L, bool PRUNE>
__device__ inline void stage16s(float2* X, int j) {
    float xr[16], xi[16];
    const int p = j & (L - 1);
#pragma unroll
    for (int t = 0; t < 16; ++t) {
        float2 v = X[SWZIDX(j + t * M)];
        xr[t] = v.x; xi[t] = v.y;
    }
    tw_apply16<SIGN>(xr, xi, ((float)SIGN * 2.f * PI_F / (float)(16 * L)) * (float)p);
    dft16<SIGN>(xr, xi);
    __syncthreads();
    const int base = 16 * j - 15 * p;
#pragma unroll
    for (int k0 = 0; k0 < 4; ++k0)
#pragma unroll
        for (int k2 = 0; k2 < 4; ++k2) {
            const int u = k0 + 4 * k2;
            if (!PRUNE || u < 8) {
                const int a = base + u * L;
                X[SWZIDX(a)] = make_float2(xr[4*k0+k2], xi[4*k0+k2]);
            }
        }
    __syncthreads();
}

// forward 4096-pt FFT, stage-0 input in registers (upper half structurally 0).
template<int SIGN, bool PRUNE>
__device__ inline void fft4096_swz_from_regs(float2* X, int tid,
                                             float xr[16], float xi[16]) {
    dft16z<SIGN>(xr, xi);
#pragma unroll
    for (int k0 = 0; k0 < 4; ++k0)
#pragma unroll
        for (int k2 = 0; k2 < 4; ++k2)
            X[SWZIDX(16 * tid + k0 + 4 * k2)] = make_float2(xr[4*k0+k2], xi[4*k0+k2]);
    __syncthreads();
    stage16s<SIGN, 256, 16,  false>(X, tid);
    stage16s<SIGN, 256, 256, PRUNE>(X, tid);
}

// full 4096-pt FFT from LDS (inverse path). PRUNE: only outputs idx<2048 stored.
template<int SIGN, bool PRUNE>
__device__ inline void fft4096_swz(float2* X, int tid) {
    float xr[16], xi[16];
#pragma unroll
    for (int t = 0; t < 16; ++t) {
        float2 v = X[SWZIDX(tid + t * 256)];
        xr[t] = v.x; xi[t] = v.y;
    }
    dft16<SIGN>(xr, xi);
    __syncthreads();
#pragma unroll
    for (int k0 = 0; k0 < 4; ++k0)
#pragma unroll
        for (int k2 = 0; k2 < 4; ++k2)
            X[SWZIDX(16 * tid + k0 + 4 * k2)] = make_float2(xr[4*k0+k2], xi[4*k0+k2]);
    __syncthreads();
    stage16s<SIGN, 256, 16,  false>(X, tid);
    stage16s<SIGN, 256, 256, PRUNE>(X, tid);
}

// ---- K_pre: blocks [0,512)    = at_roots (latency-bound; dispatched FIRST for
//                                 max wave spread across CUs);
//             blocks [512,2560) = 64x64 float4 transpose of u (BW backfill).
//      Block-level co-scheduling (verified r9); intra-block fusion fails (r7).
__global__ __launch_bounds__(256) void k_pre(const float* __restrict__ u,
                                             const float* __restrict__ p_ri,
                                             const float* __restrict__ lambda_ri,
                                             const float* __restrict__ B_ri,
                                             const float* __restrict__ Ct_ri,
                                             const float* __restrict__ log_step,
                                             float2* __restrict__ a_out,
                                             float* __restrict__ ut) {
    __shared__ float4 shbuf[1040];      // 16640 B, aliased per-branch
    const int bid = blockIdx.x;
    const int tid = threadIdx.x;

    if (bid < DMODEL * 2) {
        // ---- at_roots: 4 l's per thread -------------------------------------
        float4* c0 = shbuf;             // [64]
        float4* c1 = shbuf + 64;        // [64]
        float2* lam = (float2*)(shbuf + 128);
        const int d = bid >> 1;
        const int lbase = (bid & 1) << 10;
        if (tid < NSTATE) {
            const int n = tid;
            const float px = p_ri[2*n], py = p_ri[2*n+1];
            lam[n] = make_float2(lambda_ri[2*n], lambda_ri[2*n+1]);
            const float Bx = B_ri[(d*NSTATE+n)*2], By = B_ri[(d*NSTATE+n)*2+1];
            const float Cx = Ct_ri[(d*NSTATE+n)*2], Cy = Ct_ri[(d*NSTATE+n)*2+1];
            c0[n] = make_float4(Cx*Bx + Cy*By, Cx*By - Cy*Bx,
                                Cx*px + Cy*py, Cx*py - Cy*px);
            c1[n] = make_float4(px*Bx + py*By, px*By - py*Bx, px*px + py*py, 0.f);
        }
        __syncthreads();

        const float tos = 2.f * __expf(-log_step[d]);
        float gx[4], gy[4], ccx[4], ccy[4];
        float k00x[4], k00y[4], k01x[4], k01y[4];
        float k10x[4], k10y[4], k11x[4], k11y[4];
#pragma unroll
        for (int j = 0; j < 4; ++j) {
            const int l = lbase + tid + (j << 8);
            float sn, cs;
            sincosf(2.f * PI_F * (float)l / (float)LLEN, &sn, &cs);
            const float opx = 1.f + cs, opy = sn;
            const float omx = 1.f - cs, omy = -sn;
            const float inv_op = frcp(opx*opx + opy*opy);
            gx[j] = tos * (omx*opx + omy*opy) * inv_op;
            gy[j] = tos * (omy*opx - omx*opy) * inv_op;
            ccx[j] = 2.f * opx * inv_op; ccy[j] = -2.f * opy * inv_op;
            k00x[j]=0.f; k00y[j]=0.f; k01x[j]=0.f; k01y[j]=0.f;
            k10x[j]=0.f; k10y[j]=0.f; k11x[j]=0.f; k11y[j]=0.f;
        }
        for (int n = 0; n < NSTATE; ++n) {
            const float2 lm = lam[n];
            const float4 a = c0[n];
            const float4 b = c1[n];
#pragma unroll
            for (int j = 0; j < 4; ++j) {
                const float dx = gx[j] - lm.x, dy = gy[j] - lm.y;
                const float idn = frcp(dx*dx + dy*dy);
                const float ix = dx * idn, iy = -dy * idn;
                k00x[j] += a.x*ix - a.y*iy;  k00y[j] += a.x*iy + a.y*ix;
                k01x[j] += a.z*ix - a.w*iy;  k01y[j] += a.z*iy + a.w*ix;
                k10x[j] += b.x*ix - b.y*iy;  k10y[j] += b.x*iy + b.y*ix;
                k11x[j] += b.z*ix;           k11y[j] += b.z*iy;
            }
        }
#pragma unroll
        for (int j = 0; j < 4; ++j) {
            const float nx = k01x[j]*k10x[j] - k01y[j]*k10y[j];
            const float ny = k01x[j]*k10y[j] + k01y[j]*k10x[j];
            const float dpx = 1.f + k11x[j], dpy = k11y[j];
            const float idq = frcp(dpx*dpx + dpy*dpy);
            const float qx = (nx*dpx + ny*dpy) * idq;
            const float qy = (ny*dpx - nx*dpy) * idq;
            const float rx = k00x[j] - qx, ry = k00y[j] - qy;
            a_out[(size_t)d * LLEN + lbase + tid + (j << 8)] =
                make_float2(ccx[j]*rx - ccy[j]*ry, ccx[j]*ry + ccy[j]*rx);
        }
        return;
    }

    // ---- 64x64 float4-both-sides transpose ----------------------------------
    {
        const int blk = bid - DMODEL * 2;           // 0..2047
        const int bt0 = (blk & 511) * 64;
        const int ch0 = (blk >> 9) * 64;
        float* tile = (float*)shbuf;                // 64 x 65 floats
        const int tx4 = (tid & 15) * 4;
        const int ty  = tid >> 4;
#pragma unroll
        for (int k = 0; k < 4; ++k) {
            const int r = ty + 16 * k;
            const float4 v = *(const float4*)&u[(size_t)(bt0 + r) * DMODEL + ch0 + tx4];
            tile[r * 65 + tx4 + 0] = v.x;
            tile[r * 65 + tx4 + 1] = v.y;
            tile[r * 65 + tx4 + 2] = v.z;
            tile[r * 65 + tx4 + 3] = v.w;
        }
        __syncthreads();
#pragma unroll
        for (int k = 0; k < 4; ++k) {
            const int c = ty + 16 * k;
            float4 o;
            o.x = tile[(tx4 + 0) * 65 + c];
            o.y = tile[(tx4 + 1) * 65 + c];
            o.z = tile[(tx4 + 2) * 65 + c];
            o.w = tile[(tx4 + 3) * 65 + c];
            *(float4*)&ut[(size_t)(ch0 + c) * (NBATCH * LLEN) + bt0 + tx4] = o;
        }
    }
}

// ---- K_mixH: Khat from a (2x FFT2048 via even/odd identity), 256 blocks -----
__global__ __launch_bounds__(256, 4) void k_mixH(const float2* __restrict__ a_in,
                                                 float2* __restrict__ Hc) {
    __shared__ float2 X[LDSN2];
    const int tid = threadIdx.x;
    const int d = blockIdx.x;
    const float isc = 1.f / (float)NFFT;
    const float4* a4 = (const float4*)(a_in + (size_t)d * LLEN);
#pragma unroll
    for (int k = 0; k < 4; ++k) {
        const int v = tid + k * 256;
        const float4 w = a4[v];
        X[PADIDX(2 * v)]     = make_float2(w.x, w.y);
        X[PADIDX(2 * v + 1)] = make_float2(w.z, w.w);
    }
    __syncthreads();

    float2* H = Hc + (size_t)d * KSTRIDE;
    // even frequencies: Khat_{2m} = (a_{(-m) mod L} + conj(a_m)) / 2
    for (int m = tid; m <= 1024; m += 256) {
        const float2 am = X[PADIDX(m)];
        const float2 an = X[PADIDX((LLEN - m) & (LLEN - 1))];
        H[2 * m] = make_float2((an.x + am.x) * 0.5f * isc,
                               (an.y - am.y) * 0.5f * isc);
    }
    fft2048_f2<-1>(X, tid);     // A = F(a)

    // K_j = Re(A_j)/L ; modulate by e^{-2*pi*i*j/4096}
#pragma unroll
    for (int k = 0; k < 8; ++k) {
        const int j = tid + k * 256;
        const int q = PADIDX(j);
        const float Kj = X[q].x * (1.f / (float)LLEN);
        float snj, csj;
        __sincosf(-PI_F * (float)j * (1.f / 2048.f), &snj, &csj);
        X[q] = make_float2(Kj * csj, Kj * snj);
    }
    __syncthreads();
    fft2048_f2<-1>(X, tid);     // W_m = Khat_{2m+1}

    for (int m = tid; m < 1024; m += 256) {
        const float2 w = X[PADIDX(m)];
        H[2 * m + 1] = make_float2(w.x * isc, w.y * isc);
    }
}

// ---- K_conv: per (channel, batch-pair). r8-verified 42us configuration:
//      swizzled 32KB LDS, register-entry stage-0 (dft16z), INLINE twiddles
//      (r9: memory table spills), fused skip-add, float4 epilogue.
//      XCD swizzle: XCD x owns channels [32x,32x+32) with all 8 pairs.
__global__ __launch_bounds__(256, 4) void k_conv(const float* __restrict__ ut,
                                                 const float2* __restrict__ Hc,
                                                 const float* __restrict__ Dp,
                                                 float* __restrict__ yt) {
    __shared__ float2 X[NFFT];            // 32768 B, unpadded (SWZIDX everywhere)
    const int bid = blockIdx.x;           // 0..2047
    const int x = bid & 7;                // xcd (dispatch round-robins)
    const int s = bid >> 3;               // 0..255
    const int ch = (x << 5) | (s & 31);   // channel 0..255
    const int pair = s >> 5;              // 0..7
    const int tid = threadIdx.x;

    const float* u0 = ut + (size_t)ch * (NBATCH * LLEN) + (size_t)(2 * pair) * LLEN;
    const float* u1 = u0 + LLEN;

    float xr[16], xi[16];
#pragma unroll
    for (int k = 0; k < 8; ++k) {         // coalesced: 64 lanes x 4B dense
        xr[k] = u0[tid + k * 256];
        xi[k] = u1[tid + k * 256];
    }
    // xr/xi[8..15] are structurally zero and never read (dft16z)

    fft4096_swz_from_regs<-1, false>(X, tid, xr, xi);

    const float2* H = Hc + (size_t)ch * KSTRIDE;
    for (int f = tid; f <= NFFT / 2; f += 256) {
        const int fb = (NFFT - f) & (NFFT - 1);
        const float2 Za = X[SWZIDX(f)], Zb = X[SWZIDX(fb)];
        const float u0x = 0.5f * (Za.x + Zb.x), u0y = 0.5f * (Za.y - Zb.y);
        const float u1x = 0.5f * (Za.y + Zb.y), u1y = -0.5f * (Za.x - Zb.x);
        const float2 Ha = H[f];
        const float y0x = u0x*Ha.x - u0y*Ha.y, y0y = u0x*Ha.y + u0y*Ha.x;
        const float y1x = u1x*Ha.x - u1y*Ha.y, y1y = u1x*Ha.y + u1y*Ha.x;
        X[SWZIDX(f)] = make_float2(y0x - y1y, y0y + y1x);
        if (fb != f) {
            const float Hbx = Ha.x, Hby = -Ha.y;   // H[fb] = conj(H[f]) (K real)
            const float z0x = u0x*Hbx + u0y*Hby, z0y = u0x*Hby - u0y*Hbx;
            const float z1x = u1x*Hbx + u1y*Hby, z1y = u1x*Hby - u1y*Hbx;
            X[SWZIDX(fb)] = make_float2(z0x - z1y, z0y + z1x);
        }
    }
    __syncthreads();
    fft4096_swz<+1, true>(X, tid);        // pruned: only t<2048 stored

    const float dp = Dp[ch];
    float* y0o = yt + (size_t)ch * (NBATCH * LLEN) + (size_t)(2 * pair) * LLEN;
    float* y1o = y0o + LLEN;
#pragma unroll
    for (int k = 0; k < 2; ++k) {
        const int i0 = 4 * (tid + k * 256);           // 4-aligned, <2048
        const float2 va = X[SWZIDX(i0 + 0)];
        const float2 vb = X[SWZIDX(i0 + 1)];
        const float2 vc = X[SWZIDX(i0 + 2)];
        const float2 vd = X[SWZIDX(i0 + 3)];
        const float4 u0v = *(const float4*)&u0[i0];
        const float4 u1v = *(const float4*)&u1[i0];
        float4 o0, o1;
        o0.x = va.x + dp * u0v.x; o0.y = vb.x + dp * u0v.y;
        o0.z = vc.x + dp * u0v.z; o0.w = vd.x + dp * u0v.w;
        o1.x = va.y + dp * u1v.x; o1.y = vb.y + dp * u1v.y;
        o1.z = vc.y + dp * u1v.z; o1.w = vd.y + dp * u1v.w;
        *(float4*)&y0o[i0] = o0;
        *(float4*)&y1o[i0] = o1;
    }
}

// ---- K_post: 64x64 float4-both-sides transpose yt -> out ---------------------
__global__ __launch_bounds__(256) void k_post(const float* __restrict__ yt,
                                              float* __restrict__ out) {
    __shared__ float tile[64 * 65];       // 16640 B
    const int bt0 = (blockIdx.x & 511) * 64;
    const int ch0 = (blockIdx.x >> 9) * 64;
    const int tid = threadIdx.x;
    const int tx4 = (tid & 15) * 4;
    const int ty  = tid >> 4;
#pragma unroll
    for (int k = 0; k < 4; ++k) {
        const int r = ty + 16 * k;        // ch row 0..63
        const float4 v = *(const float4*)&yt[(size_t)(ch0 + r) * (NBATCH * LLEN) + bt0 + tx4];
        tile[r * 65 + tx4 + 0] = v.x;
        tile[r * 65 + tx4 + 1] = v.y;
        tile[r * 65 + tx4 + 2] = v.z;
        tile[r * 65 + tx4 + 3] = v.w;
    }
    __syncthreads();
#pragma unroll
    for (int k = 0; k < 4; ++k) {
        const int b = ty + 16 * k;        // bt row 0..63
        float4 o;
        o.x = tile[(tx4 + 0) * 65 + b];
        o.y = tile[(tx4 + 1) * 65 + b];
        o.z = tile[(tx4 + 2) * 65 + b];
        o.w = tile[(tx4 + 3) * 65 + b];
        *(float4*)&out[(size_t)(bt0 + b) * DMODEL + ch0 + tx4] = o;
    }
}

extern "C" void kernel_launch(void* const* d_in, const int* in_sizes, int n_in,
                              void* d_out, int out_size, void* d_ws, size_t ws_size,
                              hipStream_t stream) {
    const float* u         = (const float*)d_in[0];
    const float* p_ri      = (const float*)d_in[1];
    const float* lambda_ri = (const float*)d_in[2];
    const float* B_ri      = (const float*)d_in[3];
    const float* Ct_ri     = (const float*)d_in[4];
    const float* Dp        = (const float*)d_in[5];
    const float* log_step  = (const float*)d_in[6];
    float* out = (float*)d_out;

    // ws layout: Hc (4.21MB) | region B: a (4MB) aliased by yt (33.5MB)
    float2* Hc = (float2*)d_ws;
    char*   wb = (char*)d_ws + (size_t)DMODEL * KSTRIDE * sizeof(float2);
    float2* a  = (float2*)wb;
    float*  yt = (float*)wb;
    float*  ut = out;   // d_out doubles as transpose scratch (overwritten by k_post)

    k_pre <<<DMODEL * 2 + 2048, 256, 0, stream>>>(u, p_ri, lambda_ri, B_ri,
                                                  Ct_ri, log_step, a, ut);
    k_mixH<<<DMODEL, 256, 0, stream>>>(a, Hc);
    k_conv<<<DMODEL * (NBATCH / 2), 256, 0, stream>>>(ut, Hc, Dp, yt);
    k_post<<<2048, 256, 0, stream>>>(yt, out);
}